// Round 1
// 467.328 us; speedup vs baseline: 1.0114x; 1.0114x over previous
//
#include <hip/hip_runtime.h>

// Shapes fixed by the reference: D=128 features, E=128 edges, B=4096 batch.
constexpr int D    = 128;
constexpr int E    = 128;
constexpr int BB   = 4096;
constexpr int ROWS = 8;      // batch rows per prep2 block

typedef float f32x4 __attribute__((ext_vector_type(4)));

// NO workspace use. Scratch lives inside d_out (race-free by stream ordering
// + column exclusivity), float offsets:
//   v[b,0:D]  at out[b*D + d]               (e=0 slice)      prep2 -> att(b)
//   c[b]      at out[(BB+b)*D]              (e=1 slice)      prep2 -> att(b)
//   G[k,d]    at out[2*BB*D + k*D + d]      (e=2 slice head) gwh  -> prep2
//   h[d]      at out[3*BB*D + d]; beta at out[3*BB*D + D]    gwh  -> prep2
// att_main block b reads ONLY its own column's v/c before overwriting; the
// G/h/beta region is read only by prep2, which completes (stream order)
// before att_main overwrites it with final e=2/e=3 output.

// ---------------------------------------------------------------------------
// gwh: G = W^T W, h = b @ W, beta = b.b.
// Algebra: v = (T@W^T + b)@W = T@G + h ;  c = m_i.b = T.h + beta.
// 128 blocks (one G row each) x 128 threads. ~3 us.
// ---------------------------------------------------------------------------
__global__ __launch_bounds__(128) void gwh_kernel(
    const float* __restrict__ W, const float* __restrict__ bias, float* out)
{
    __shared__ float Wl[D][D];   // 64 KB
    __shared__ float bl[D];
    const int t = threadIdx.x;
    const int r = blockIdx.x;

    const float4* W4 = (const float4*)W;
    float4* Wl4 = (float4*)&Wl[0][0];
    for (int i = t; i < D * D / 4; i += 128) Wl4[i] = W4[i];
    bl[t] = bias[t];
    __syncthreads();

    // G[r][t] = sum_k W[k][r] * W[k][t]   (broadcast + stride-1: conflict-free)
    float acc = 0.f;
    for (int k = 0; k < D; ++k) acc += Wl[k][r] * Wl[k][t];
    out[(size_t)2 * BB * D + r * D + t] = acc;

    if (r == 0) {
        float hh = 0.f;
        for (int f = 0; f < D; ++f) hh += bl[f] * Wl[f][t];
        out[(size_t)3 * BB * D + t] = hh;
        if (t == 0) {
            float b2 = 0.f;
            for (int f = 0; f < D; ++f) b2 += bl[f] * bl[f];
            out[(size_t)3 * BB * D + D] = b2;
        }
    }
}

// ---------------------------------------------------------------------------
// prep2: v[b,:] = T[b,:]@G + h ; c[b] = T[b,:].h + beta.
// 512 blocks x 256 threads, 8 rows per block, 4 rows per thread.
// Single GEMM pass (half the MACs of the old chained m->v version), one sync.
// ---------------------------------------------------------------------------
__global__ __launch_bounds__(256) void prep2_kernel(
    const float* __restrict__ T, float* out)
{
    __shared__ float Gl[D][D];      // 64 KB
    __shared__ float Tl[ROWS][D];   // 4 KB
    __shared__ float hl[D];
    __shared__ float beta_s;

    const int t  = threadIdx.x;
    const int b0 = blockIdx.x * ROWS;

    {
        const float4* Gs = (const float4*)(out + (size_t)2 * BB * D);
        float4* Gd = (float4*)&Gl[0][0];
        for (int i = t; i < D * D / 4; i += 256) Gd[i] = Gs[i];
        const float4* Ts = (const float4*)(T + (size_t)b0 * D);
        ((float4*)&Tl[0][0])[t] = Ts[t];          // 256 float4 == ROWS*D
        if (t < D) hl[t] = out[(size_t)3 * BB * D + t];
        if (t == 0) beta_s = out[(size_t)3 * BB * D + D];
    }
    __syncthreads();

    const int dc = t & 127;          // output column d
    const int r0 = (t >> 7) * 4;     // this thread's 4 rows
    float a0 = hl[dc], a1 = hl[dc], a2 = hl[dc], a3 = hl[dc];
    #pragma unroll 4
    for (int k = 0; k < D; k += 4) {
        // G column reads: lanes = consecutive dc -> 2 lanes/bank, free.
        const float g0 = Gl[k + 0][dc], g1 = Gl[k + 1][dc],
                    g2 = Gl[k + 2][dc], g3 = Gl[k + 3][dc];
        // T reads: wave-uniform address -> b128 broadcast, free.
        const float4 t0 = *(const float4*)&Tl[r0 + 0][k];
        const float4 t1 = *(const float4*)&Tl[r0 + 1][k];
        const float4 t2 = *(const float4*)&Tl[r0 + 2][k];
        const float4 t3 = *(const float4*)&Tl[r0 + 3][k];
        a0 += t0.x * g0 + t0.y * g1 + t0.z * g2 + t0.w * g3;
        a1 += t1.x * g0 + t1.y * g1 + t1.z * g2 + t1.w * g3;
        a2 += t2.x * g0 + t2.y * g1 + t2.z * g2 + t2.w * g3;
        a3 += t3.x * g0 + t3.y * g1 + t3.z * g2 + t3.w * g3;
    }
    out[(size_t)(b0 + r0 + 0) * D + dc] = a0;
    out[(size_t)(b0 + r0 + 1) * D + dc] = a1;
    out[(size_t)(b0 + r0 + 2) * D + dc] = a2;
    out[(size_t)(b0 + r0 + 3) * D + dc] = a3;

    // c[b] = T[b,:].h + beta : 8 rows x 32 lanes, vectorized + butterfly.
    const int cr = t >> 5, cl = t & 31;
    const float4 tc = *(const float4*)&Tl[cr][cl * 4];
    const float4 hc = *(const float4*)&hl[cl * 4];
    float p = tc.x * hc.x + tc.y * hc.y + tc.z * hc.z + tc.w * hc.w;
    #pragma unroll
    for (int msk = 16; msk >= 1; msk >>= 1) p += __shfl_xor(p, msk);
    if (cl == 0) out[(size_t)(BB + b0 + cr) * D] = p + beta_s;
}

// ---------------------------------------------------------------------------
// main: one block per batch index b. 256 threads = 8 edge-groups x 32 lanes.
// Full E x D slice register-resident (64 VGPR). S is read exactly once and
// out written exactly once -> non-temporal (zero-reuse streaming, keep L2
// clean). e_ij[e] = S[e,b,:].v[b,:] + c[b]; edge-sum in double; scale+store.
// ---------------------------------------------------------------------------
__global__ __launch_bounds__(256) void att_main(
    const float* __restrict__ S, float* out)
{
    const int b  = blockIdx.x;
    const int t  = threadIdx.x;
    const int lc = t & 31;   // float4 chunk within row (d = lc*4 .. lc*4+3)
    const int eb = t >> 5;   // 0..7, edge within iteration group

    __shared__ float sc[E];
    __shared__ float inv_s;

    const f32x4* Sp = (const f32x4*)S;
    const f32x4  v4 = ((const f32x4*)(out + (size_t)b * D))[lc]; // v scratch
    const float  c  = out[(size_t)(BB + b) * D];                 // c scratch

    f32x4 s[16];
    #pragma unroll
    for (int i = 0; i < 16; ++i) {
        const int e = i * 8 + eb;
        s[i] = __builtin_nontemporal_load(Sp + ((size_t)e * BB + b) * 32 + lc);
    }

    // Scores: per-lane dot4, butterfly over the 32 lanes of the d-dimension.
    #pragma unroll
    for (int i = 0; i < 16; ++i) {
        float p = s[i].x * v4.x + s[i].y * v4.y + s[i].z * v4.z + s[i].w * v4.w;
        #pragma unroll
        for (int msk = 16; msk >= 1; msk >>= 1) p += __shfl_xor(p, msk);
        if (lc == 0) sc[i * 8 + eb] = p + c;
    }
    __syncthreads();

    // Sum over the 128 edges in double (cancellation-safe), one wave.
    if (t < 64) {
        double d0 = (double)sc[t] + (double)sc[t + 64];
        #pragma unroll
        for (int msk = 32; msk >= 1; msk >>= 1) d0 += __shfl_xor(d0, msk);
        if (t == 0) inv_s = (float)(1.0 / d0);
    }
    __syncthreads();

    const float inv = inv_s;
    f32x4* Op = (f32x4*)out;
    #pragma unroll
    for (int i = 0; i < 16; ++i) {
        const int e = i * 8 + eb;
        const float w = sc[e] * inv;      // LDS broadcast within group
        f32x4 o = s[i] * w;
        __builtin_nontemporal_store(o, Op + ((size_t)e * BB + b) * 32 + lc);
    }
}

extern "C" void kernel_launch(void* const* d_in, const int* in_sizes, int n_in,
                              void* d_out, int out_size, void* d_ws, size_t ws_size,
                              hipStream_t stream) {
    // d_in: [0]=true_batch_size(int,1) [1]=T[B,D] [2]=S[E,B,D] [3]=W[D,D] [4]=b[D]
    const float* T    = (const float*)d_in[1];
    const float* S    = (const float*)d_in[2];
    const float* W    = (const float*)d_in[3];
    const float* bias = (const float*)d_in[4];
    float* out        = (float*)d_out;

    gwh_kernel<<<D, D, 0, stream>>>(W, bias, out);
    prep2_kernel<<<BB / ROWS, 256, 0, stream>>>(T, out);
    att_main<<<BB, 256, 0, stream>>>(S, out);
}

// Round 2
// 465.703 us; speedup vs baseline: 1.0150x; 1.0035x over previous
//
#include <hip/hip_runtime.h>

// Shapes fixed by the reference: D=128 features, E=128 edges, B=4096 batch.
constexpr int D    = 128;
constexpr int E    = 128;
constexpr int BB   = 4096;
constexpr int ROWS = 8;      // batch rows per prep2 block (fallback path)

typedef float f32x4 __attribute__((ext_vector_type(4)));

// Algebra: m_i = T@W^T + b ; v = m_i@W = T@(W^T W) + b@W = T@G + h
//          c   = m_i . b   = T.h + beta          (h = b@W, beta = b.b)
// e_ij[e,b] = S[e,b,:].v[b,:] + c[b]
//
// Primary path (ws_size >= 64.5 KB): P = d_ws holds [G (D*D) | h (D) | beta].
//   gwh -> att_fused. att_fused computes v,c per-block (GEMV hidden under the
//   S HBM stream), so no scratch ever touches d_out.
// Fallback path (tiny/absent ws): P lives at out[2*BB*D ...] (e=2 slice head),
//   race-free by stream ordering: prep2 consumes P before att_main overwrites.

// ---------------------------------------------------------------------------
// gwh: P = [G = W^T W | h = b@W | beta = b.b]. 128 blocks x 128 threads, ~3us.
// ---------------------------------------------------------------------------
__global__ __launch_bounds__(128) void gwh_kernel(
    const float* __restrict__ W, const float* __restrict__ bias, float* P)
{
    __shared__ float Wl[D][D];   // 64 KB
    __shared__ float bl[D];
    const int t = threadIdx.x;
    const int r = blockIdx.x;

    const float4* W4 = (const float4*)W;
    float4* Wl4 = (float4*)&Wl[0][0];
    for (int i = t; i < D * D / 4; i += 128) Wl4[i] = W4[i];
    bl[t] = bias[t];
    __syncthreads();

    // G[r][t] = sum_k W[k][r] * W[k][t]   (broadcast + stride-1: conflict-free)
    float acc = 0.f;
    for (int k = 0; k < D; ++k) acc += Wl[k][r] * Wl[k][t];
    P[r * D + t] = acc;

    if (r == 0) {
        float hh = 0.f;
        for (int f = 0; f < D; ++f) hh += bl[f] * Wl[f][t];
        P[D * D + t] = hh;
        if (t == 0) {
            float b2 = 0.f;
            for (int f = 0; f < D; ++f) b2 += bl[f] * bl[f];
            P[D * D + D] = b2;
        }
    }
}

// ---------------------------------------------------------------------------
// att_fused (primary): one block per batch b. 256 threads = 8 edge-groups x
// 32 lanes. Issues the full E x D register-resident S stream FIRST (16 nt
// dwordx4 loads in flight), then computes v[b,:] = T[b,:]@G + h (64 FMA per
// thread, G reads are coalesced L2 hits) and c under that latency.
// ---------------------------------------------------------------------------
__global__ __launch_bounds__(256) void att_fused(
    const float* __restrict__ S, const float* __restrict__ T,
    const float* __restrict__ P, float* out)
{
    const int b  = blockIdx.x;
    const int t  = threadIdx.x;
    const int lc = t & 31;   // float4 chunk within row (d = lc*4 .. lc*4+3)
    const int eb = t >> 5;   // 0..7, edge within iteration group

    __shared__ float vl[2][D];   // k-split partial v
    __shared__ float sc[E];
    __shared__ float inv_s, c_s;

    const f32x4* Sp = (const f32x4*)S;

    // Issue the HBM stream first: 16 independent nt loads per thread.
    f32x4 s[16];
    #pragma unroll
    for (int i = 0; i < 16; ++i) {
        const int e = i * 8 + eb;
        s[i] = __builtin_nontemporal_load(Sp + ((size_t)e * BB + b) * 32 + lc);
    }

    // v partial: thread covers output col d = t&127 over half the k range.
    {
        const int d  = t & 127;
        const int kh = (t >> 7) * 64;
        const float* Trow = T + (size_t)b * D;   // L2-hot (2 MiB total)
        float acc = 0.f;
        #pragma unroll 8
        for (int kk = 0; kk < 64; ++kk)
            acc += Trow[kh + kk] * P[(size_t)(kh + kk) * D + d];
        vl[t >> 7][d] = acc;
    }
    // c = T[b,:].h + beta  (lanes 0..31 of wave 0)
    if (t < 32) {
        const f32x4 t4 = ((const f32x4*)(T + (size_t)b * D))[t];
        const f32x4 h4 = ((const f32x4*)(P + D * D))[t];
        float p = t4.x * h4.x + t4.y * h4.y + t4.z * h4.z + t4.w * h4.w;
        #pragma unroll
        for (int m = 16; m >= 1; m >>= 1) p += __shfl_xor(p, m);
        if (t == 0) c_s = p + P[D * D + D];
    }
    __syncthreads();

    f32x4 v4;
    {
        const f32x4 va = ((const f32x4*)&vl[0][0])[lc];
        const f32x4 vb = ((const f32x4*)&vl[1][0])[lc];
        const f32x4 h4 = ((const f32x4*)(P + D * D))[lc];
        v4 = va + vb + h4;
    }
    const float c = c_s;

    // Scores: per-lane dot4, butterfly over the 32 lanes of the d-dimension.
    #pragma unroll
    for (int i = 0; i < 16; ++i) {
        float p = s[i].x * v4.x + s[i].y * v4.y + s[i].z * v4.z + s[i].w * v4.w;
        #pragma unroll
        for (int m = 16; m >= 1; m >>= 1) p += __shfl_xor(p, m);
        if (lc == 0) sc[i * 8 + eb] = p + c;
    }
    __syncthreads();

    // Sum over the 128 edges in double (cancellation-safe), one wave.
    if (t < 64) {
        double d0 = (double)sc[t] + (double)sc[t + 64];
        #pragma unroll
        for (int m = 32; m >= 1; m >>= 1) d0 += __shfl_xor(d0, m);
        if (t == 0) inv_s = (float)(1.0 / d0);
    }
    __syncthreads();

    const float inv = inv_s;
    f32x4* Op = (f32x4*)out;
    #pragma unroll
    for (int i = 0; i < 16; ++i) {
        const int e = i * 8 + eb;
        const float w = sc[e] * inv;      // LDS broadcast within group
        __builtin_nontemporal_store(s[i] * w, Op + ((size_t)e * BB + b) * 32 + lc);
    }
}

// ---------------------------------------------------------------------------
// Fallback path (ws absent/too small): prep2 + att_main, scratch in d_out.
//   v[b,:] at out[b*D ...] (e=0), c[b] at out[(BB+b)*D] (e=1), P at e=2 head.
// ---------------------------------------------------------------------------
__global__ __launch_bounds__(256) void prep2_kernel(
    const float* __restrict__ T, const float* __restrict__ P, float* out)
{
    __shared__ float Gl[D][D];      // 64 KB
    __shared__ float Tl[ROWS][D];   // 4 KB
    __shared__ float hl[D];
    __shared__ float beta_s;

    const int t  = threadIdx.x;
    const int b0 = blockIdx.x * ROWS;

    {
        const float4* Gs = (const float4*)P;
        float4* Gd = (float4*)&Gl[0][0];
        for (int i = t; i < D * D / 4; i += 256) Gd[i] = Gs[i];
        const float4* Ts = (const float4*)(T + (size_t)b0 * D);
        ((float4*)&Tl[0][0])[t] = Ts[t];          // 256 float4 == ROWS*D
        if (t < D) hl[t] = P[D * D + t];
        if (t == 0) beta_s = P[D * D + D];
    }
    __syncthreads();

    const int dc = t & 127;          // output column d
    const int r0 = (t >> 7) * 4;     // this thread's 4 rows
    float a0 = hl[dc], a1 = hl[dc], a2 = hl[dc], a3 = hl[dc];
    #pragma unroll 4
    for (int k = 0; k < D; k += 4) {
        const float g0 = Gl[k + 0][dc], g1 = Gl[k + 1][dc],
                    g2 = Gl[k + 2][dc], g3 = Gl[k + 3][dc];
        const float4 t0 = *(const float4*)&Tl[r0 + 0][k];
        const float4 t1 = *(const float4*)&Tl[r0 + 1][k];
        const float4 t2 = *(const float4*)&Tl[r0 + 2][k];
        const float4 t3 = *(const float4*)&Tl[r0 + 3][k];
        a0 += t0.x * g0 + t0.y * g1 + t0.z * g2 + t0.w * g3;
        a1 += t1.x * g0 + t1.y * g1 + t1.z * g2 + t1.w * g3;
        a2 += t2.x * g0 + t2.y * g1 + t2.z * g2 + t2.w * g3;
        a3 += t3.x * g0 + t3.y * g1 + t3.z * g2 + t3.w * g3;
    }
    out[(size_t)(b0 + r0 + 0) * D + dc] = a0;
    out[(size_t)(b0 + r0 + 1) * D + dc] = a1;
    out[(size_t)(b0 + r0 + 2) * D + dc] = a2;
    out[(size_t)(b0 + r0 + 3) * D + dc] = a3;

    const int cr = t >> 5, cl = t & 31;
    const float4 tc = *(const float4*)&Tl[cr][cl * 4];
    const float4 hc = *(const float4*)&hl[cl * 4];
    float p = tc.x * hc.x + tc.y * hc.y + tc.z * hc.z + tc.w * hc.w;
    #pragma unroll
    for (int msk = 16; msk >= 1; msk >>= 1) p += __shfl_xor(p, msk);
    if (cl == 0) out[(size_t)(BB + b0 + cr) * D] = p + beta_s;
}

__global__ __launch_bounds__(256) void att_main(
    const float* __restrict__ S, float* out)
{
    const int b  = blockIdx.x;
    const int t  = threadIdx.x;
    const int lc = t & 31;
    const int eb = t >> 5;

    __shared__ float sc[E];
    __shared__ float inv_s;

    const f32x4* Sp = (const f32x4*)S;
    const f32x4  v4 = ((const f32x4*)(out + (size_t)b * D))[lc];
    const float  c  = out[(size_t)(BB + b) * D];

    f32x4 s[16];
    #pragma unroll
    for (int i = 0; i < 16; ++i) {
        const int e = i * 8 + eb;
        s[i] = __builtin_nontemporal_load(Sp + ((size_t)e * BB + b) * 32 + lc);
    }

    #pragma unroll
    for (int i = 0; i < 16; ++i) {
        float p = s[i].x * v4.x + s[i].y * v4.y + s[i].z * v4.z + s[i].w * v4.w;
        #pragma unroll
        for (int msk = 16; msk >= 1; msk >>= 1) p += __shfl_xor(p, msk);
        if (lc == 0) sc[i * 8 + eb] = p + c;
    }
    __syncthreads();

    if (t < 64) {
        double d0 = (double)sc[t] + (double)sc[t + 64];
        #pragma unroll
        for (int msk = 32; msk >= 1; msk >>= 1) d0 += __shfl_xor(d0, msk);
        if (t == 0) inv_s = (float)(1.0 / d0);
    }
    __syncthreads();

    const float inv = inv_s;
    f32x4* Op = (f32x4*)out;
    #pragma unroll
    for (int i = 0; i < 16; ++i) {
        const int e = i * 8 + eb;
        const float w = sc[e] * inv;
        __builtin_nontemporal_store(s[i] * w, Op + ((size_t)e * BB + b) * 32 + lc);
    }
}

extern "C" void kernel_launch(void* const* d_in, const int* in_sizes, int n_in,
                              void* d_out, int out_size, void* d_ws, size_t ws_size,
                              hipStream_t stream) {
    // d_in: [0]=true_batch_size(int,1) [1]=T[B,D] [2]=S[E,B,D] [3]=W[D,D] [4]=b[D]
    const float* T    = (const float*)d_in[1];
    const float* S    = (const float*)d_in[2];
    const float* W    = (const float*)d_in[3];
    const float* bias = (const float*)d_in[4];
    float* out        = (float*)d_out;

    const size_t need = (size_t)(D * D + D + 1) * sizeof(float);
    if (d_ws != nullptr && ws_size >= need) {
        float* P = (float*)d_ws;
        gwh_kernel<<<D, D, 0, stream>>>(W, bias, P);
        att_fused<<<BB, 256, 0, stream>>>(S, T, P, out);
    } else {
        float* P = out + (size_t)2 * BB * D;   // e=2 slice head (stream-ordered)
        gwh_kernel<<<D, D, 0, stream>>>(W, bias, P);
        prep2_kernel<<<BB / ROWS, 256, 0, stream>>>(T, P, out);
        att_main<<<BB, 256, 0, stream>>>(S, out);
    }
}